// Round 3
// baseline (600.623 us; speedup 1.0000x reference)
//
#include <hip/hip_runtime.h>
#include <hip/hip_bf16.h>
#include <math.h>

// Problem constants
#define B_  8
#define C_  64
#define H_  256
#define W_  256
#define HW_ (H_*W_)
#define J_  192          // 3*C intermediate channels
#define TH_ 32           // K2 tile height

typedef __attribute__((ext_vector_type(8))) short short8;
typedef __attribute__((ext_vector_type(4))) float f32x4;

// ---- bf16 helpers (RNE) ----
__device__ __forceinline__ ushort f2bf(float f) {
    union { float f; uint u; } v; v.f = f;
    uint u = v.u;
    return (ushort)((u + 0x7fffu + ((u >> 16) & 1u)) >> 16);
}
__device__ __forceinline__ float bf2f(ushort s) {
    union { uint u; float f; } v; v.u = ((uint)s) << 16;
    return v.f;
}
__device__ __forceinline__ uint pk(float a, float b) {
    return (uint)f2bf(a) | ((uint)f2bf(b) << 16);
}

// Gaussian taps (1D, normalized) as compile-time constants; separable product
// equals the reference's normalized 2D kernel to fp32 rounding.
constexpr float G0_[5]  = {2.6386598e-04f, 1.06450312e-01f, 7.86572828e-01f,
                           1.06450312e-01f, 2.6386598e-04f};
constexpr float G1_[7]  = {4.4330482e-03f, 5.40055826e-02f, 2.42036229e-01f,
                           3.99050280e-01f, 2.42036229e-01f, 5.40055826e-02f,
                           4.4330482e-03f};
constexpr float G2_[13] = {2.2181980e-03f, 8.7731300e-03f, 2.7023161e-02f,
                           6.4825174e-02f, 1.21109411e-01f, 1.76213165e-01f,
                           1.99675640e-01f, 1.76213165e-01f, 1.21109411e-01f,
                           6.4825174e-02f, 2.7023161e-02f, 8.7731300e-03f,
                           2.2181980e-03f};

// ---------------------------------------------------------------------------
// K1: v[b, j, px] = sum_c Wm[j,c] * x[b,c,px]   (bf16 out), via MFMA.
//   Wm[j][c] = fw[(j&63)*192 + (j>>6)*64 + c]   (mix commutes with blur)
// Round-3 change: all 16 staging loads issued before any conversion (MLP).
// ---------------------------------------------------------------------------
__global__ __launch_bounds__(256) void k1_mix(
    const float* __restrict__ x, const float* __restrict__ fw,
    ushort* __restrict__ v)
{
    __shared__ ushort lxs[256 * 64];   // 32 KB

    const int b      = blockIdx.x >> 8;
    const int pxbase = (blockIdx.x & 255) << 8;
    const int t      = threadIdx.x;
    const int lane   = t & 63;
    const int wv_    = t >> 6;

    // ---- stage x [64c x 256px] fp32 -> LDS bf16 transposed ----
    {
        const int cg = lane;            // px-quad group 0..63
        const float* xb = x + (size_t)b * C_ * HW_ + pxbase + 4 * cg;
        float4 r[16];
#pragma unroll
        for (int i = 0; i < 4; ++i) {
#pragma unroll
            for (int rr = 0; rr < 4; ++rr)
                r[i * 4 + rr] = *(const float4*)(xb + (size_t)(wv_ * 4 + i * 16 + rr) * HW_);
        }
#pragma unroll
        for (int i = 0; i < 4; ++i) {
            const int c4 = wv_ + i * 4;         // granule index
            const float4 r0 = r[i*4+0], r1 = r[i*4+1], r2 = r[i*4+2], r3 = r[i*4+3];
            const int sbase = c4 ^ (cg & 15);
            ushort* dst = &lxs[(4 * cg) * 64];
            *(uint2*)(dst + 0*64 + ((sbase ^ 0) * 4)) = make_uint2(pk(r0.x, r1.x), pk(r2.x, r3.x));
            *(uint2*)(dst + 1*64 + ((sbase ^ 4) * 4)) = make_uint2(pk(r0.y, r1.y), pk(r2.y, r3.y));
            *(uint2*)(dst + 2*64 + ((sbase ^ 8) * 4)) = make_uint2(pk(r0.z, r1.z), pk(r2.z, r3.z));
            *(uint2*)(dst + 3*64 + ((sbase ^ 12) * 4)) = make_uint2(pk(r0.w, r1.w), pk(r2.w, r3.w));
        }
    }

    // ---- W fragments (B operand), 3 j-tiles per wave, kept in regs ----
    const int n = lane & 15;           // j within tile / B-frag col
    const int q = lane >> 4;           // quad
    union Frag { short8 v; uint u[4]; };
    Frag wf[3][2];
#pragma unroll
    for (int i = 0; i < 3; ++i) {
        const int j  = (wv_ * 3 + i) * 16 + n;
        const float* wr = fw + (size_t)(j & 63) * J_ + (j >> 6) * 64;
#pragma unroll
        for (int kh = 0; kh < 2; ++kh) {
            float4 w0 = *(const float4*)(wr + kh * 32 + q * 8);
            float4 w1 = *(const float4*)(wr + kh * 32 + q * 8 + 4);
            wf[i][kh].u[0] = pk(w0.x, w0.y);
            wf[i][kh].u[1] = pk(w0.z, w0.w);
            wf[i][kh].u[2] = pk(w1.x, w1.y);
            wf[i][kh].u[3] = pk(w1.z, w1.w);
        }
    }

    __syncthreads();

    // ---- 16 px-tiles x 3 j-tiles ----
    for (int mt = 0; mt < 16; ++mt) {
        const int px = mt * 16 + (lane & 15);          // A-frag m
        const ushort* row = &lxs[px * 64];
        const int s = ((px >> 2) & 15) ^ ((px & 3) << 2);
        Frag a0, a1;
        {
            uint2 lo  = *(const uint2*)&row[((2*q    ) ^ s) * 4];
            uint2 hi  = *(const uint2*)&row[((2*q + 1) ^ s) * 4];
            a0.u[0] = lo.x;  a0.u[1] = lo.y;  a0.u[2] = hi.x;  a0.u[3] = hi.y;
            uint2 lo1 = *(const uint2*)&row[((8 + 2*q    ) ^ s) * 4];
            uint2 hi1 = *(const uint2*)&row[((8 + 2*q + 1) ^ s) * 4];
            a1.u[0] = lo1.x; a1.u[1] = lo1.y; a1.u[2] = hi1.x; a1.u[3] = hi1.y;
        }
#pragma unroll
        for (int i = 0; i < 3; ++i) {
            f32x4 acc = {0.f, 0.f, 0.f, 0.f};
            acc = __builtin_amdgcn_mfma_f32_16x16x32_bf16(a0.v, wf[i][0].v, acc, 0, 0, 0);
            acc = __builtin_amdgcn_mfma_f32_16x16x32_bf16(a1.v, wf[i][1].v, acc, 0, 0, 0);
            const int j   = (wv_ * 3 + i) * 16 + n;
            const int pxg = pxbase + mt * 16 + q * 4;  // D row = q*4 + reg
            *(uint2*)&v[(size_t)(b * J_ + j) * HW_ + pxg] =
                make_uint2(pk(acc[0], acc[1]), pk(acc[2], acc[3]));
        }
    }
}

// ---------------------------------------------------------------------------
// K2 (round-3 rewrite): NO LDS, NO barriers. Block = (b, o, 32-row tile);
// thread owns 4 cols x 8 rows. Per scale, thread h-blurs its own 8+2R halo
// rows (coalesced 8B granule loads; L1 absorbs the column-window overlap)
// and scatter-accumulates the v-blur into 8 float4 register accumulators.
// All loop indices compile-time (full unroll) so taps fold to literals.
// ---------------------------------------------------------------------------
template<int R, int G>
__device__ __forceinline__ void blur_scale(
    const ushort* __restrict__ vplane, const float (&g)[2 * R + 1],
    int h0, int base, int cg, float4* acc)
{
    constexpr int NG  = 2 * G + 1;     // 8B granules per row window
    constexpr int OFF = 4 * G - R;     // first tap offset inside window
    constexpr int NK  = 8 + 2 * R;     // input rows this thread touches

#pragma unroll
    for (int k = 0; k < NK; ++k) {
        const int gh = h0 + base - R + k;
        float b0 = 0.f, b1 = 0.f, b2 = 0.f, b3 = 0.f;
        if ((unsigned)gh < (unsigned)H_) {
            const ushort* vr = vplane + (size_t)gh * W_;
            float win[NG * 4];
#pragma unroll
            for (int gi = 0; gi < NG; ++gi) {
                const int gg = cg - G + gi;
                uint2 d = ((unsigned)gg < 64u) ? *(const uint2*)(vr + gg * 4)
                                               : make_uint2(0u, 0u);
                win[gi*4+0] = bf2f((ushort)(d.x & 0xffffu));
                win[gi*4+1] = bf2f((ushort)(d.x >> 16));
                win[gi*4+2] = bf2f((ushort)(d.y & 0xffffu));
                win[gi*4+3] = bf2f((ushort)(d.y >> 16));
            }
#pragma unroll
            for (int d = 0; d <= 2 * R; ++d) {
                const float gd = g[d];
                b0 += gd * win[OFF + d + 0];
                b1 += gd * win[OFF + d + 1];
                b2 += gd * win[OFF + d + 2];
                b3 += gd * win[OFF + d + 3];
            }
        }
        // v-blur scatter: input row (base-R+k) feeds output rows i with
        // tap index d = k - i, 0 <= d <= 2R (compile-time per (k,i)).
#pragma unroll
        for (int i = 0; i < 8; ++i) {
            if (k - i >= 0 && k - i <= 2 * R) {
                const float gd = g[k - i];
                acc[i].x += gd * b0;
                acc[i].y += gd * b1;
                acc[i].z += gd * b2;
                acc[i].w += gd * b3;
            }
        }
    }
}

__global__ __launch_bounds__(256) void k2_blur(
    const ushort* __restrict__ v, const float* __restrict__ x,
    const float* __restrict__ bias, float* __restrict__ out)
{
    const int t    = blockIdx.x;
    const int tile = t & 7;
    const int o    = (t >> 3) & 63;
    const int b    = t >> 9;
    const int h0   = tile * TH_;
    const int cg   = threadIdx.x & 63;   // 4-col group
    const int rw   = threadIdx.x >> 6;   // 8-row band
    const int c0   = cg * 4;
    const int base = rw * 8;

    float4 acc[8];
#pragma unroll
    for (int i = 0; i < 8; ++i) acc[i] = make_float4(0.f, 0.f, 0.f, 0.f);

    const ushort* vp = v + (size_t)(b * J_ + o) * HW_;
    blur_scale<2, 1>(vp,                        G0_, h0, base, cg, acc);
    blur_scale<3, 1>(vp + (size_t)C_ * HW_,     G1_, h0, base, cg, acc);
    blur_scale<6, 2>(vp + (size_t)(2*C_) * HW_, G2_, h0, base, cg, acc);

    // epilogue: + x + bias
    const float* xp = x   + ((size_t)b * C_ + o) * HW_ + (size_t)h0 * W_;
    float*       op = out + ((size_t)b * C_ + o) * HW_ + (size_t)h0 * W_;
    const float bo = bias[o];
#pragma unroll
    for (int i = 0; i < 8; ++i) {
        const int row = base + i;
        float4 xv = *(const float4*)&xp[(size_t)row * W_ + c0];
        float4 r;
        r.x = xv.x + bo + acc[i].x;
        r.y = xv.y + bo + acc[i].y;
        r.z = xv.z + bo + acc[i].z;
        r.w = xv.w + bo + acc[i].w;
        *(float4*)&op[(size_t)row * W_ + c0] = r;
    }
}

extern "C" void kernel_launch(void* const* d_in, const int* in_sizes, int n_in,
                              void* d_out, int out_size, void* d_ws, size_t ws_size,
                              hipStream_t stream)
{
    const float* x  = (const float*)d_in[0];
    const float* fw = (const float*)d_in[1];
    const float* fb = (const float*)d_in[2];
    float* out = (float*)d_out;
    ushort* v = (ushort*)d_ws;   // bf16 intermediate, 201 MB (ws proven large
                                 // enough in round 1: full 196608 KB written)

    k1_mix<<<dim3(B_ * (HW_ / 256)), dim3(256), 0, stream>>>(x, fw, v);
    k2_blur<<<dim3(B_ * C_ * (H_ / TH_)), dim3(256), 0, stream>>>(v, x, fb, out);
}